// Round 6
// baseline (2422.909 us; speedup 1.0000x reference)
//
#include <hip/hip_runtime.h>

// Problem constants (from reference)
#define N_U 100000
#define N_V 100000
#define OO 64
#define RR 5
#define EE 500000
#define TOT_E (RR * EE)   // 2,500,000 edges per direction
#define NB 782            // buckets of 128 dst nodes (781*128=99968, last=32)

typedef short bf16x8 __attribute__((ext_vector_type(8)));
typedef float f32x4 __attribute__((ext_vector_type(4)));

__device__ __forceinline__ float bf2f(unsigned short u) {
  union { unsigned int i; float f; } x;
  x.i = ((unsigned int)u) << 16;
  return x.f;
}
__device__ __forceinline__ unsigned short f2bf(float f) {
  union { float f; unsigned int i; } x;
  x.f = f;
  unsigned int lsb = (x.i >> 16) & 1u;
  unsigned int r = x.i + 0x7fffu + lsb;   // round-to-nearest-even
  return (unsigned short)(r >> 16);
}

// ---------------------------------------------------------------------------
// Cumsum the per-relation fp32 weights, write bf16 in MFMA B-fragment order.
// bfrag layout: [side(2)=u,v][r(5)][4096]
// ---------------------------------------------------------------------------
__global__ void prep_weights(const float* __restrict__ wu,
                             const float* __restrict__ wv,
                             unsigned short* __restrict__ bfrag) {
  int side = blockIdx.x;
  const float* w = side ? wv : wu;
  for (int idx = threadIdx.x; idx < 4096; idx += 256) {
    int d = idx >> 6, o = idx & 63;
    int c = o >> 4, n = o & 15;
    int sk = d >> 5, q = (d >> 3) & 3, jj = d & 7;
    int f = c * 2 + sk;
    int lane = q * 16 + n;
    int pos = (f * 64 + lane) * 8 + jj;
    float acc = 0.f;
    for (int r = 0; r < RR; ++r) {
      acc += w[r * 4096 + idx];
      bfrag[(side * RR + r) * 4096 + pos] = f2bf(acc);
    }
  }
}

// ---------------------------------------------------------------------------
// All-5-relations GEMM: tmp5[r] = X @ Wcum[r], bf16, lane-permuted row layout
// tmp_r[row*64 + m*4 + c] = D[row][c*16+m] (8 B/lane stores).
// ---------------------------------------------------------------------------
__global__ __launch_bounds__(256) void gemm5_kernel(
    const float* __restrict__ X,
    const unsigned short* __restrict__ bfrag_side,  // [r(5)][4096]
    unsigned short* __restrict__ tmp5) {            // [r(5)][100000][64]
  __shared__ unsigned short smem[RR * 4096];
  for (int idx = threadIdx.x; idx < RR * 4096; idx += 256)
    smem[idx] = bfrag_side[idx];
  __syncthreads();

  int lane = threadIdx.x & 63;
  int wave = threadIdx.x >> 6;
  int q = lane >> 4, m = lane & 15;
  int t = blockIdx.x * 4 + wave;
  if (t >= N_U / 16) return;
  int r0 = t * 16;

  const float* xr = X + (size_t)(r0 + m) * 64;
  float4 p0 = *(const float4*)(xr + q * 8);
  float4 p1 = *(const float4*)(xr + q * 8 + 4);
  float4 p2 = *(const float4*)(xr + 32 + q * 8);
  float4 p3 = *(const float4*)(xr + 32 + q * 8 + 4);
  bf16x8 a0, a1;
  a0[0] = (short)f2bf(p0.x); a0[1] = (short)f2bf(p0.y);
  a0[2] = (short)f2bf(p0.z); a0[3] = (short)f2bf(p0.w);
  a0[4] = (short)f2bf(p1.x); a0[5] = (short)f2bf(p1.y);
  a0[6] = (short)f2bf(p1.z); a0[7] = (short)f2bf(p1.w);
  a1[0] = (short)f2bf(p2.x); a1[1] = (short)f2bf(p2.y);
  a1[2] = (short)f2bf(p2.z); a1[3] = (short)f2bf(p2.w);
  a1[4] = (short)f2bf(p3.x); a1[5] = (short)f2bf(p3.y);
  a1[6] = (short)f2bf(p3.z); a1[7] = (short)f2bf(p3.w);

  for (int r = 0; r < RR; ++r) {
    f32x4 acc[4];
#pragma unroll
    for (int c = 0; c < 4; ++c) {
      bf16x8 b0 = *(const bf16x8*)(smem + r * 4096 + ((c * 2 + 0) * 64 + lane) * 8);
      bf16x8 b1 = *(const bf16x8*)(smem + r * 4096 + ((c * 2 + 1) * 64 + lane) * 8);
      f32x4 a = {0.f, 0.f, 0.f, 0.f};
      a = __builtin_amdgcn_mfma_f32_16x16x32_bf16(a0, b0, a, 0, 0, 0);
      a = __builtin_amdgcn_mfma_f32_16x16x32_bf16(a1, b1, a, 0, 0, 0);
      acc[c] = a;
    }
    unsigned short* trow = tmp5 + (size_t)r * N_U * 64;
#pragma unroll
    for (int i = 0; i < 4; ++i) {
      ushort4 o;
      o.x = f2bf(acc[0][i]); o.y = f2bf(acc[1][i]);
      o.z = f2bf(acc[2][i]); o.w = f2bf(acc[3][i]);
      *(ushort4*)(trow + (size_t)(r0 + q * 4 + i) * 64 + m * 4) = o;
    }
  }
}

// ---------------------------------------------------------------------------
// Bucket histogram: LDS-binned, ~782 global atomics per block.
// ghist must be pre-zeroed. Grid: 306 blocks x 8192 edges.
// ---------------------------------------------------------------------------
__global__ __launch_bounds__(256) void bucket_hist(
    const int* __restrict__ dst, unsigned* __restrict__ ghist) {
  __shared__ unsigned cnt[NB];
  for (int i = threadIdx.x; i < NB; i += 256) cnt[i] = 0u;
  __syncthreads();
  int base = blockIdx.x * 8192;
#pragma unroll 4
  for (int g = 0; g < 32; ++g) {
    int e = base + g * 256 + threadIdx.x;
    if (e < TOT_E) atomicAdd(&cnt[dst[e] >> 7], 1u);
  }
  __syncthreads();
  for (int b = threadIdx.x; b < NB; b += 256)
    if (cnt[b]) atomicAdd(&ghist[b], cnt[b]);
}

// ---------------------------------------------------------------------------
// Single-block exclusive scan of ghist[NB] -> gbase[NB+1] and gcursor[NB].
// ---------------------------------------------------------------------------
__global__ __launch_bounds__(256) void bucket_scan(
    const unsigned* __restrict__ ghist, unsigned* __restrict__ gbase,
    unsigned* __restrict__ gcursor) {
  __shared__ unsigned wsum[4];
  int tid = threadIdx.x, lane = tid & 63, wave = tid >> 6;
  unsigned c[4]; unsigned s = 0;
#pragma unroll
  for (int k = 0; k < 4; ++k) {
    int i = tid * 4 + k;
    c[k] = (i < NB) ? ghist[i] : 0u;
    s += c[k];
  }
  unsigned incl = s;
#pragma unroll
  for (int d = 1; d < 64; d <<= 1) {
    unsigned t = __shfl_up(incl, d);
    if (lane >= d) incl += t;
  }
  if (lane == 63) wsum[wave] = incl;
  __syncthreads();
  unsigned woff = 0;
  for (int w = 0; w < 4; ++w) if (w < wave) woff += wsum[w];
  unsigned base = woff + (incl - s);
#pragma unroll
  for (int k = 0; k < 4; ++k) {
    int i = tid * 4 + k;
    if (i < NB) { gbase[i] = base; gcursor[i] = base; }
    base += c[k];
  }
  if (tid == 255) gbase[NB] = base;   // == TOT_E
}

// ---------------------------------------------------------------------------
// Multi-split scatter: per block, LDS-count its 8192 edges per bucket, reserve
// one contiguous payload range per (block,bucket) via a single global atomic,
// then write runs (~10 entries avg -> ~84 B contiguous) coherently.
// payload entry = val_bits<<32 | dstLow(7b)<<19 | (r*N_U + src)(19b)
// ---------------------------------------------------------------------------
__global__ __launch_bounds__(256) void bucket_scatter(
    const int* __restrict__ dst, const int* __restrict__ src,
    const float* __restrict__ val, unsigned* __restrict__ gcursor,
    unsigned long long* __restrict__ payload) {
  __shared__ unsigned cnt[NB];
  for (int i = threadIdx.x; i < NB; i += 256) cnt[i] = 0u;
  __syncthreads();
  int base = blockIdx.x * 8192;
#pragma unroll 4
  for (int g = 0; g < 32; ++g) {
    int e = base + g * 256 + threadIdx.x;
    if (e < TOT_E) atomicAdd(&cnt[dst[e] >> 7], 1u);
  }
  __syncthreads();
  for (int b = threadIdx.x; b < NB; b += 256) {
    unsigned c = cnt[b];
    cnt[b] = c ? atomicAdd(&gcursor[b], c) : 0u;
  }
  __syncthreads();
#pragma unroll 2
  for (int g = 0; g < 32; ++g) {
    int e = base + g * 256 + threadIdx.x;
    if (e < TOT_E) {
      int d = dst[e];
      int r = e / EE;
      unsigned key = ((unsigned)(d & 127) << 19) | (unsigned)(r * N_U + src[e]);
      union { float f; unsigned u; } v; v.f = val[e];
      unsigned pos = atomicAdd(&cnt[d >> 7], 1u);
      payload[pos] = ((unsigned long long)v.u << 32) | key;
    }
  }
}

// ---------------------------------------------------------------------------
// Bucket aggregate: one block per bucket. LDS z[128][64] fp32 (32 KB),
// stream the bucket's contiguous payload, gather lane-permuted tmp rows,
// ds_add accumulate (2-way bank alias = free), coalesced relu+bias writeout.
// ---------------------------------------------------------------------------
__global__ __launch_bounds__(256) void bucket_agg(
    const unsigned long long* __restrict__ payload,
    const unsigned* __restrict__ gbase,
    const unsigned short* __restrict__ tmp5,
    const float* __restrict__ bias, float* __restrict__ out) {
  __shared__ float z[128 * 64];   // 32 KB
  int b = blockIdx.x;
  for (int i = threadIdx.x; i < 128 * 64; i += 256) z[i] = 0.f;
  __syncthreads();

  int lane = threadIdx.x & 63;
  int wave = threadIdx.x >> 6;
  int ppos = (lane & 15) * 4 + (lane >> 4);   // position of output col `lane`

  int s = (int)gbase[b], e = (int)gbase[b + 1];
  int n = e - s;
  int len = (n + 3) >> 2;
  int k0 = s + wave * len;
  int k1 = k0 + len; if (k1 > e) k1 = e;

  int k = k0;
  for (; k + 3 < k1; k += 4) {
    unsigned long long p0 = payload[k + 0];
    unsigned long long p1 = payload[k + 1];
    unsigned long long p2 = payload[k + 2];
    unsigned long long p3 = payload[k + 3];
    union { unsigned u; float f; } v0, v1, v2, v3;
    v0.u = (unsigned)(p0 >> 32); v1.u = (unsigned)(p1 >> 32);
    v2.u = (unsigned)(p2 >> 32); v3.u = (unsigned)(p3 >> 32);
    unsigned q0 = (unsigned)p0, q1 = (unsigned)p1, q2 = (unsigned)p2, q3 = (unsigned)p3;
    float t0 = bf2f(tmp5[(size_t)(q0 & 0x7FFFFu) * 64 + ppos]);
    float t1 = bf2f(tmp5[(size_t)(q1 & 0x7FFFFu) * 64 + ppos]);
    float t2 = bf2f(tmp5[(size_t)(q2 & 0x7FFFFu) * 64 + ppos]);
    float t3 = bf2f(tmp5[(size_t)(q3 & 0x7FFFFu) * 64 + ppos]);
    atomicAdd(&z[((q0 >> 19) & 127u) * 64 + ppos], v0.f * t0);
    atomicAdd(&z[((q1 >> 19) & 127u) * 64 + ppos], v1.f * t1);
    atomicAdd(&z[((q2 >> 19) & 127u) * 64 + ppos], v2.f * t2);
    atomicAdd(&z[((q3 >> 19) & 127u) * 64 + ppos], v3.f * t3);
  }
  for (; k < k1; ++k) {
    unsigned long long p0 = payload[k];
    union { unsigned u; float f; } v0; v0.u = (unsigned)(p0 >> 32);
    unsigned q0 = (unsigned)p0;
    float t0 = bf2f(tmp5[(size_t)(q0 & 0x7FFFFu) * 64 + ppos]);
    atomicAdd(&z[((q0 >> 19) & 127u) * 64 + ppos], v0.f * t0);
  }
  __syncthreads();

  int nb0 = b * 128;
  int nodes = N_U - nb0 < 128 ? N_U - nb0 : 128;
  for (int idx = threadIdx.x; idx < nodes * 64; idx += 256) {
    int nl = idx >> 6, j = idx & 63;
    float zz = z[nl * 64 + ((j & 15) * 4 + (j >> 4))];
    out[(size_t)(nb0 + nl) * 64 + j] = fmaxf(zz + bias[j], 0.f);
  }
}

// ===========================================================================
// FALLBACK PATH (proven R4 atomic-scatter version, used if ws is small)
// ===========================================================================
__global__ __launch_bounds__(256) void gemm_kernel(
    const float* __restrict__ X, const unsigned short* __restrict__ bfrag,
    unsigned short* __restrict__ tmp) {
  int lane = threadIdx.x & 63;
  int wave = threadIdx.x >> 6;
  int q = lane >> 4, m = lane & 15;
  bf16x8 bf[8];
#pragma unroll
  for (int f = 0; f < 8; ++f)
    bf[f] = *(const bf16x8*)(bfrag + (f * 64 + lane) * 8);
  int t = blockIdx.x * 4 + wave;
  if (t >= N_U / 16) return;
  int r0 = t * 16;
  const float* xr = X + (size_t)(r0 + m) * 64;
  float4 p0 = *(const float4*)(xr + q * 8);
  float4 p1 = *(const float4*)(xr + q * 8 + 4);
  float4 p2 = *(const float4*)(xr + 32 + q * 8);
  float4 p3 = *(const float4*)(xr + 32 + q * 8 + 4);
  bf16x8 a0, a1;
  a0[0] = (short)f2bf(p0.x); a0[1] = (short)f2bf(p0.y);
  a0[2] = (short)f2bf(p0.z); a0[3] = (short)f2bf(p0.w);
  a0[4] = (short)f2bf(p1.x); a0[5] = (short)f2bf(p1.y);
  a0[6] = (short)f2bf(p1.z); a0[7] = (short)f2bf(p1.w);
  a1[0] = (short)f2bf(p2.x); a1[1] = (short)f2bf(p2.y);
  a1[2] = (short)f2bf(p2.z); a1[3] = (short)f2bf(p2.w);
  a1[4] = (short)f2bf(p3.x); a1[5] = (short)f2bf(p3.y);
  a1[6] = (short)f2bf(p3.z); a1[7] = (short)f2bf(p3.w);
#pragma unroll
  for (int c = 0; c < 4; ++c) {
    f32x4 acc = {0.f, 0.f, 0.f, 0.f};
    acc = __builtin_amdgcn_mfma_f32_16x16x32_bf16(a0, bf[c * 2 + 0], acc, 0, 0, 0);
    acc = __builtin_amdgcn_mfma_f32_16x16x32_bf16(a1, bf[c * 2 + 1], acc, 0, 0, 0);
#pragma unroll
    for (int i = 0; i < 4; ++i)
      tmp[(size_t)(r0 + q * 4 + i) * 64 + c * 16 + m] = f2bf(acc[i]);
  }
}

__global__ __launch_bounds__(256) void scatter_kernel(
    const unsigned short* __restrict__ tmp, const float* __restrict__ edge_val,
    const int* __restrict__ dst_idx, const int* __restrict__ src_idx,
    float* __restrict__ z, int base, int cnt) {
  int e = blockIdx.x * 4 + (threadIdx.x >> 6);
  int j = threadIdx.x & 63;
  int d = dst_idx[e] - base;
  if ((unsigned)d >= (unsigned)cnt) return;
  int s = src_idx[e];
  float w = edge_val[e];
  atomicAdd(&z[(size_t)d * 64 + j], w * bf2f(tmp[(size_t)s * 64 + j]));
}

__global__ __launch_bounds__(256) void finalize_kernel(
    const float* __restrict__ z, const float* __restrict__ bias,
    float* __restrict__ out) {
  size_t i4 = ((size_t)blockIdx.x * 256 + threadIdx.x) * 4;
  float4 zz = *(const float4*)(z + i4);
  const float4 bb = *(const float4*)(bias + (i4 & 63));
  float4 o;
  o.x = fmaxf(zz.x + bb.x, 0.f);
  o.y = fmaxf(zz.y + bb.y, 0.f);
  o.z = fmaxf(zz.z + bb.z, 0.f);
  o.w = fmaxf(zz.w + bb.w, 0.f);
  *(float4*)(out + i4) = o;
}

extern "C" void kernel_launch(void* const* d_in, const int* in_sizes, int n_in,
                              void* d_out, int out_size, void* d_ws, size_t ws_size,
                              hipStream_t stream) {
  const float* x_u      = (const float*)d_in[0];
  const float* x_v      = (const float*)d_in[1];
  const float* w_u      = (const float*)d_in[2];
  const float* w_v      = (const float*)d_in[3];
  const float* bias_u   = (const float*)d_in[4];
  const float* bias_v   = (const float*)d_in[5];
  const float* edge_val = (const float*)d_in[6];
  const int*   edge_u   = (const int*)d_in[7];
  const int*   edge_v   = (const int*)d_in[8];
  float* out = (float*)d_out;
  char* ws = (char*)d_ws;

  // Fast-path ws layout:
  //   bfrag   @ 0           131,072 (uses 81,920)
  //   tmp5    @ 131,072     5*100000*64*2 = 64,000,000
  //   ghist   @ 64,131,072  4,096 (NB u32)
  //   gbase   @ 64,135,168  4,096 (NB+1 u32)
  //   gcursor @ 64,139,264  4,096
  //   payload @ 64,143,360  2,500,000*8 = 20,000,000 -> end 84,143,360
  const size_t FAST_NEED = 84935936;   // R5-proven size bound

  unsigned short* bfrag = (unsigned short*)ws;
  prep_weights<<<2, 256, 0, stream>>>(w_u, w_v, bfrag);

  if (ws_size >= FAST_NEED) {
    unsigned short* tmp5    = (unsigned short*)(ws + 131072);
    unsigned*       ghist   = (unsigned*)(ws + 64131072);
    unsigned*       gbase   = (unsigned*)(ws + 64135168);
    unsigned*       gcursor = (unsigned*)(ws + 64139264);
    unsigned long long* payload = (unsigned long long*)(ws + 64143360);

    const int edge_grid = (TOT_E + 8191) / 8192;  // 306
    const int gemm_grid = (N_U / 16 + 3) / 4;     // 1563

    for (int side = 0; side < 2; ++side) {
      // side 0: out_u <- tmp of x_v @ Wcum_v, dst=edge_u, src=edge_v
      // side 1: out_v <- tmp of x_u @ Wcum_u, dst=edge_v, src=edge_u
      const float* X = side ? x_u : x_v;
      const unsigned short* frag0 = bfrag + (side ? 0 : RR * 4096);
      const int* dst = side ? edge_v : edge_u;
      const int* src = side ? edge_u : edge_v;
      const float* bias = side ? bias_v : bias_u;
      float* out_side = out + (size_t)side * N_U * OO;

      gemm5_kernel<<<gemm_grid, 256, 0, stream>>>(X, frag0, tmp5);
      hipMemsetAsync(ghist, 0, NB * 4, stream);
      bucket_hist<<<edge_grid, 256, 0, stream>>>(dst, ghist);
      bucket_scan<<<1, 256, 0, stream>>>(ghist, gbase, gcursor);
      bucket_scatter<<<edge_grid, 256, 0, stream>>>(dst, src, edge_val, gcursor, payload);
      bucket_agg<<<NB, 256, 0, stream>>>(payload, gbase, tmp5, bias, out_side);
    }
    return;
  }

  // ---------------- Fallback: proven R4 path ----------------
  unsigned short* tmp = (unsigned short*)(ws + 131072);
  float*          z   = (float*)(ws + 131072 + 12800000);
  const size_t fixed = 131072 + 12800000;
  size_t zbytes = ws_size > fixed ? ws_size - fixed : 0;
  long chunk = (long)(zbytes / (OO * 4));
  chunk -= chunk % 16;
  if (chunk < 16) chunk = 16;
  if (chunk > N_U) chunk = N_U;

  const int gemm_grid = (N_U / 16 + 3) / 4;
  const int scat_grid = EE / 4;

  for (int side = 0; side < 2; ++side) {
    const float* X = side ? x_u : x_v;
    const unsigned short* frag0 = bfrag + (side ? 0 : RR * 4096);
    const int* dst = side ? edge_v : edge_u;
    const int* src = side ? edge_u : edge_v;
    const float* bias = side ? bias_v : bias_u;
    float* out_side = out + (size_t)side * N_U * OO;

    for (long base = 0; base < N_U; base += chunk) {
      long cnt = N_U - base < chunk ? N_U - base : chunk;
      hipMemsetAsync(z, 0, (size_t)cnt * OO * 4, stream);
      for (int r = 0; r < RR; ++r) {
        gemm_kernel<<<gemm_grid, 256, 0, stream>>>(X, frag0 + r * 4096, tmp);
        scatter_kernel<<<scat_grid, 256, 0, stream>>>(
            tmp, edge_val + (size_t)r * EE, dst + (size_t)r * EE,
            src + (size_t)r * EE, z, (int)base, (int)cnt);
      }
      finalize_kernel<<<(int)(cnt / 16), 256, 0, stream>>>(
          z, bias, out_side + base * OO);
    }
  }
}

// Round 7
// 2392.594 us; speedup vs baseline: 1.0127x; 1.0127x over previous
//
#include <hip/hip_runtime.h>

// Problem constants (from reference)
#define N_U 100000
#define N_V 100000
#define OO 64
#define RR 5
#define EE 500000
#define TOT_E (RR * EE)   // 2,500,000 edges per direction
#define NB 782            // buckets of 128 dst nodes (781*128=99968, last=32)

typedef short bf16x8 __attribute__((ext_vector_type(8)));
typedef float f32x4 __attribute__((ext_vector_type(4)));

__device__ __forceinline__ float bf2f(unsigned short u) {
  union { unsigned int i; float f; } x;
  x.i = ((unsigned int)u) << 16;
  return x.f;
}
__device__ __forceinline__ unsigned short f2bf(float f) {
  union { float f; unsigned int i; } x;
  x.f = f;
  unsigned int lsb = (x.i >> 16) & 1u;
  unsigned int r = x.i + 0x7fffu + lsb;   // round-to-nearest-even
  return (unsigned short)(r >> 16);
}

// ---------------------------------------------------------------------------
// Cumsum the per-relation fp32 weights, write bf16 in MFMA B-fragment order.
// bfrag layout: [side(2)=u,v][r(5)][4096]
// ---------------------------------------------------------------------------
__global__ void prep_weights(const float* __restrict__ wu,
                             const float* __restrict__ wv,
                             unsigned short* __restrict__ bfrag) {
  int side = blockIdx.x;
  const float* w = side ? wv : wu;
  for (int idx = threadIdx.x; idx < 4096; idx += 256) {
    int d = idx >> 6, o = idx & 63;
    int c = o >> 4, n = o & 15;
    int sk = d >> 5, q = (d >> 3) & 3, jj = d & 7;
    int f = c * 2 + sk;
    int lane = q * 16 + n;
    int pos = (f * 64 + lane) * 8 + jj;
    float acc = 0.f;
    for (int r = 0; r < RR; ++r) {
      acc += w[r * 4096 + idx];
      bfrag[(side * RR + r) * 4096 + pos] = f2bf(acc);
    }
  }
}

// ---------------------------------------------------------------------------
// All-5-relations GEMM: tmp5[r] = X @ Wcum[r], bf16, lane-permuted row layout
// tmp_r[row*64 + m*4 + c] = D[row][c*16+m] (8 B/lane stores).
// ---------------------------------------------------------------------------
__global__ __launch_bounds__(256) void gemm5_kernel(
    const float* __restrict__ X,
    const unsigned short* __restrict__ bfrag_side,  // [r(5)][4096]
    unsigned short* __restrict__ tmp5) {            // [r(5)][100000][64]
  __shared__ unsigned short smem[RR * 4096];
  for (int idx = threadIdx.x; idx < RR * 4096; idx += 256)
    smem[idx] = bfrag_side[idx];
  __syncthreads();

  int lane = threadIdx.x & 63;
  int wave = threadIdx.x >> 6;
  int q = lane >> 4, m = lane & 15;
  int t = blockIdx.x * 4 + wave;
  if (t >= N_U / 16) return;
  int r0 = t * 16;

  const float* xr = X + (size_t)(r0 + m) * 64;
  float4 p0 = *(const float4*)(xr + q * 8);
  float4 p1 = *(const float4*)(xr + q * 8 + 4);
  float4 p2 = *(const float4*)(xr + 32 + q * 8);
  float4 p3 = *(const float4*)(xr + 32 + q * 8 + 4);
  bf16x8 a0, a1;
  a0[0] = (short)f2bf(p0.x); a0[1] = (short)f2bf(p0.y);
  a0[2] = (short)f2bf(p0.z); a0[3] = (short)f2bf(p0.w);
  a0[4] = (short)f2bf(p1.x); a0[5] = (short)f2bf(p1.y);
  a0[6] = (short)f2bf(p1.z); a0[7] = (short)f2bf(p1.w);
  a1[0] = (short)f2bf(p2.x); a1[1] = (short)f2bf(p2.y);
  a1[2] = (short)f2bf(p2.z); a1[3] = (short)f2bf(p2.w);
  a1[4] = (short)f2bf(p3.x); a1[5] = (short)f2bf(p3.y);
  a1[6] = (short)f2bf(p3.z); a1[7] = (short)f2bf(p3.w);

  for (int r = 0; r < RR; ++r) {
    f32x4 acc[4];
#pragma unroll
    for (int c = 0; c < 4; ++c) {
      bf16x8 b0 = *(const bf16x8*)(smem + r * 4096 + ((c * 2 + 0) * 64 + lane) * 8);
      bf16x8 b1 = *(const bf16x8*)(smem + r * 4096 + ((c * 2 + 1) * 64 + lane) * 8);
      f32x4 a = {0.f, 0.f, 0.f, 0.f};
      a = __builtin_amdgcn_mfma_f32_16x16x32_bf16(a0, b0, a, 0, 0, 0);
      a = __builtin_amdgcn_mfma_f32_16x16x32_bf16(a1, b1, a, 0, 0, 0);
      acc[c] = a;
    }
    unsigned short* trow = tmp5 + (size_t)r * N_U * 64;
#pragma unroll
    for (int i = 0; i < 4; ++i) {
      ushort4 o;
      o.x = f2bf(acc[0][i]); o.y = f2bf(acc[1][i]);
      o.z = f2bf(acc[2][i]); o.w = f2bf(acc[3][i]);
      *(ushort4*)(trow + (size_t)(r0 + q * 4 + i) * 64 + m * 4) = o;
    }
  }
}

// ---------------------------------------------------------------------------
// Bucket histogram: LDS-binned, ~782 global atomics per block.
// ---------------------------------------------------------------------------
__global__ __launch_bounds__(256) void bucket_hist(
    const int* __restrict__ dst, unsigned* __restrict__ ghist) {
  __shared__ unsigned cnt[NB];
  for (int i = threadIdx.x; i < NB; i += 256) cnt[i] = 0u;
  __syncthreads();
  int base = blockIdx.x * 8192;
#pragma unroll 4
  for (int g = 0; g < 32; ++g) {
    int e = base + g * 256 + threadIdx.x;
    if (e < TOT_E) atomicAdd(&cnt[dst[e] >> 7], 1u);
  }
  __syncthreads();
  for (int b = threadIdx.x; b < NB; b += 256)
    if (cnt[b]) atomicAdd(&ghist[b], cnt[b]);
}

// ---------------------------------------------------------------------------
// Single-block exclusive scan of ghist[NB] -> gbase[NB+1] and gcursor[NB].
// ---------------------------------------------------------------------------
__global__ __launch_bounds__(256) void bucket_scan(
    const unsigned* __restrict__ ghist, unsigned* __restrict__ gbase,
    unsigned* __restrict__ gcursor) {
  __shared__ unsigned wsum[4];
  int tid = threadIdx.x, lane = tid & 63, wave = tid >> 6;
  unsigned c[4]; unsigned s = 0;
#pragma unroll
  for (int k = 0; k < 4; ++k) {
    int i = tid * 4 + k;
    c[k] = (i < NB) ? ghist[i] : 0u;
    s += c[k];
  }
  unsigned incl = s;
#pragma unroll
  for (int d = 1; d < 64; d <<= 1) {
    unsigned t = __shfl_up(incl, d);
    if (lane >= d) incl += t;
  }
  if (lane == 63) wsum[wave] = incl;
  __syncthreads();
  unsigned woff = 0;
  for (int w = 0; w < 4; ++w) if (w < wave) woff += wsum[w];
  unsigned base = woff + (incl - s);
#pragma unroll
  for (int k = 0; k < 4; ++k) {
    int i = tid * 4 + k;
    if (i < NB) { gbase[i] = base; gcursor[i] = base; }
    base += c[k];
  }
  if (tid == 255) gbase[NB] = base;   // == TOT_E
}

// ---------------------------------------------------------------------------
// Multi-split scatter: per block, LDS-count its 8192 edges per bucket, reserve
// one contiguous payload range per (block,bucket) via a single global atomic,
// then write runs (~10 entries avg -> ~84 B contiguous) coherently.
// payload entry = val_bits<<32 | dstLow(7b)<<19 | (r*N_U + src)(19b)
// ---------------------------------------------------------------------------
__global__ __launch_bounds__(256) void bucket_scatter(
    const int* __restrict__ dst, const int* __restrict__ src,
    const float* __restrict__ val, unsigned* __restrict__ gcursor,
    unsigned long long* __restrict__ payload) {
  __shared__ unsigned cnt[NB];
  for (int i = threadIdx.x; i < NB; i += 256) cnt[i] = 0u;
  __syncthreads();
  int base = blockIdx.x * 8192;
#pragma unroll 4
  for (int g = 0; g < 32; ++g) {
    int e = base + g * 256 + threadIdx.x;
    if (e < TOT_E) atomicAdd(&cnt[dst[e] >> 7], 1u);
  }
  __syncthreads();
  for (int b = threadIdx.x; b < NB; b += 256) {
    unsigned c = cnt[b];
    cnt[b] = c ? atomicAdd(&gcursor[b], c) : 0u;
  }
  __syncthreads();
#pragma unroll 2
  for (int g = 0; g < 32; ++g) {
    int e = base + g * 256 + threadIdx.x;
    if (e < TOT_E) {
      int d = dst[e];
      int r = e / EE;
      unsigned key = ((unsigned)(d & 127) << 19) | (unsigned)(r * N_U + src[e]);
      union { float f; unsigned u; } v; v.f = val[e];
      unsigned pos = atomicAdd(&cnt[d >> 7], 1u);
      payload[pos] = ((unsigned long long)v.u << 32) | key;
    }
  }
}

// ---------------------------------------------------------------------------
// Bucket aggregate: one block of 1024 threads (16 waves) per bucket.
// LDS z[128][64] fp32 (32 KB); each wave takes 1/16 of the bucket payload,
// gathers lane-permuted tmp rows (one 128 B coalesced read per entry),
// LDS-atomic accumulate (2-way bank alias = free), coalesced writeout.
// VGPR<=64 required for 8 waves/SIMD -> 2 blocks/CU -> 32 waves/CU.
// ---------------------------------------------------------------------------
#define AGG_WAVES 16
__global__ __launch_bounds__(1024) void bucket_agg(
    const unsigned long long* __restrict__ payload,
    const unsigned* __restrict__ gbase,
    const unsigned short* __restrict__ tmp5,
    const float* __restrict__ bias, float* __restrict__ out) {
  __shared__ float z[128 * 64];   // 32 KB
  int b = blockIdx.x;
  for (int i = threadIdx.x; i < 128 * 64; i += 1024) z[i] = 0.f;
  __syncthreads();

  int lane = threadIdx.x & 63;
  int wave = threadIdx.x >> 6;
  int ppos = (lane & 15) * 4 + (lane >> 4);   // position of output col `lane`

  int s = (int)gbase[b], e = (int)gbase[b + 1];
  int n = e - s;
  int len = (n + AGG_WAVES - 1) / AGG_WAVES;
  int k0 = s + wave * len;
  int k1 = k0 + len; if (k1 > e) k1 = e;

  int k = k0;
  for (; k + 3 < k1; k += 4) {
    unsigned long long p0 = payload[k + 0];
    unsigned long long p1 = payload[k + 1];
    unsigned long long p2 = payload[k + 2];
    unsigned long long p3 = payload[k + 3];
    union { unsigned u; float f; } v0, v1, v2, v3;
    v0.u = (unsigned)(p0 >> 32); v1.u = (unsigned)(p1 >> 32);
    v2.u = (unsigned)(p2 >> 32); v3.u = (unsigned)(p3 >> 32);
    unsigned q0 = (unsigned)p0, q1 = (unsigned)p1, q2 = (unsigned)p2, q3 = (unsigned)p3;
    float t0 = bf2f(tmp5[(size_t)(q0 & 0x7FFFFu) * 64 + ppos]);
    float t1 = bf2f(tmp5[(size_t)(q1 & 0x7FFFFu) * 64 + ppos]);
    float t2 = bf2f(tmp5[(size_t)(q2 & 0x7FFFFu) * 64 + ppos]);
    float t3 = bf2f(tmp5[(size_t)(q3 & 0x7FFFFu) * 64 + ppos]);
    atomicAdd(&z[((q0 >> 19) & 127u) * 64 + ppos], v0.f * t0);
    atomicAdd(&z[((q1 >> 19) & 127u) * 64 + ppos], v1.f * t1);
    atomicAdd(&z[((q2 >> 19) & 127u) * 64 + ppos], v2.f * t2);
    atomicAdd(&z[((q3 >> 19) & 127u) * 64 + ppos], v3.f * t3);
  }
  for (; k < k1; ++k) {
    unsigned long long p0 = payload[k];
    union { unsigned u; float f; } v0; v0.u = (unsigned)(p0 >> 32);
    unsigned q0 = (unsigned)p0;
    float t0 = bf2f(tmp5[(size_t)(q0 & 0x7FFFFu) * 64 + ppos]);
    atomicAdd(&z[((q0 >> 19) & 127u) * 64 + ppos], v0.f * t0);
  }
  __syncthreads();

  int nb0 = b * 128;
  int nodes = N_U - nb0 < 128 ? N_U - nb0 : 128;
  for (int idx = threadIdx.x; idx < nodes * 64; idx += 1024) {
    int nl = idx >> 6, j = idx & 63;
    float zz = z[nl * 64 + ((j & 15) * 4 + (j >> 4))];
    out[(size_t)(nb0 + nl) * 64 + j] = fmaxf(zz + bias[j], 0.f);
  }
}

// ===========================================================================
// FALLBACK PATH (proven R4 atomic-scatter version, used if ws is small)
// ===========================================================================
__global__ __launch_bounds__(256) void gemm_kernel(
    const float* __restrict__ X, const unsigned short* __restrict__ bfrag,
    unsigned short* __restrict__ tmp) {
  int lane = threadIdx.x & 63;
  int wave = threadIdx.x >> 6;
  int q = lane >> 4, m = lane & 15;
  bf16x8 bf[8];
#pragma unroll
  for (int f = 0; f < 8; ++f)
    bf[f] = *(const bf16x8*)(bfrag + (f * 64 + lane) * 8);
  int t = blockIdx.x * 4 + wave;
  if (t >= N_U / 16) return;
  int r0 = t * 16;
  const float* xr = X + (size_t)(r0 + m) * 64;
  float4 p0 = *(const float4*)(xr + q * 8);
  float4 p1 = *(const float4*)(xr + q * 8 + 4);
  float4 p2 = *(const float4*)(xr + 32 + q * 8);
  float4 p3 = *(const float4*)(xr + 32 + q * 8 + 4);
  bf16x8 a0, a1;
  a0[0] = (short)f2bf(p0.x); a0[1] = (short)f2bf(p0.y);
  a0[2] = (short)f2bf(p0.z); a0[3] = (short)f2bf(p0.w);
  a0[4] = (short)f2bf(p1.x); a0[5] = (short)f2bf(p1.y);
  a0[6] = (short)f2bf(p1.z); a0[7] = (short)f2bf(p1.w);
  a1[0] = (short)f2bf(p2.x); a1[1] = (short)f2bf(p2.y);
  a1[2] = (short)f2bf(p2.z); a1[3] = (short)f2bf(p2.w);
  a1[4] = (short)f2bf(p3.x); a1[5] = (short)f2bf(p3.y);
  a1[6] = (short)f2bf(p3.z); a1[7] = (short)f2bf(p3.w);
#pragma unroll
  for (int c = 0; c < 4; ++c) {
    f32x4 acc = {0.f, 0.f, 0.f, 0.f};
    acc = __builtin_amdgcn_mfma_f32_16x16x32_bf16(a0, bf[c * 2 + 0], acc, 0, 0, 0);
    acc = __builtin_amdgcn_mfma_f32_16x16x32_bf16(a1, bf[c * 2 + 1], acc, 0, 0, 0);
#pragma unroll
    for (int i = 0; i < 4; ++i)
      tmp[(size_t)(r0 + q * 4 + i) * 64 + c * 16 + m] = f2bf(acc[i]);
  }
}

__global__ __launch_bounds__(256) void scatter_kernel(
    const unsigned short* __restrict__ tmp, const float* __restrict__ edge_val,
    const int* __restrict__ dst_idx, const int* __restrict__ src_idx,
    float* __restrict__ z, int base, int cnt) {
  int e = blockIdx.x * 4 + (threadIdx.x >> 6);
  int j = threadIdx.x & 63;
  int d = dst_idx[e] - base;
  if ((unsigned)d >= (unsigned)cnt) return;
  int s = src_idx[e];
  float w = edge_val[e];
  atomicAdd(&z[(size_t)d * 64 + j], w * bf2f(tmp[(size_t)s * 64 + j]));
}

__global__ __launch_bounds__(256) void finalize_kernel(
    const float* __restrict__ z, const float* __restrict__ bias,
    float* __restrict__ out) {
  size_t i4 = ((size_t)blockIdx.x * 256 + threadIdx.x) * 4;
  float4 zz = *(const float4*)(z + i4);
  const float4 bb = *(const float4*)(bias + (i4 & 63));
  float4 o;
  o.x = fmaxf(zz.x + bb.x, 0.f);
  o.y = fmaxf(zz.y + bb.y, 0.f);
  o.z = fmaxf(zz.z + bb.z, 0.f);
  o.w = fmaxf(zz.w + bb.w, 0.f);
  *(float4*)(out + i4) = o;
}

extern "C" void kernel_launch(void* const* d_in, const int* in_sizes, int n_in,
                              void* d_out, int out_size, void* d_ws, size_t ws_size,
                              hipStream_t stream) {
  const float* x_u      = (const float*)d_in[0];
  const float* x_v      = (const float*)d_in[1];
  const float* w_u      = (const float*)d_in[2];
  const float* w_v      = (const float*)d_in[3];
  const float* bias_u   = (const float*)d_in[4];
  const float* bias_v   = (const float*)d_in[5];
  const float* edge_val = (const float*)d_in[6];
  const int*   edge_u   = (const int*)d_in[7];
  const int*   edge_v   = (const int*)d_in[8];
  float* out = (float*)d_out;
  char* ws = (char*)d_ws;

  // Fast-path ws layout:
  //   bfrag   @ 0           131,072 (uses 81,920)
  //   tmp5    @ 131,072     5*100000*64*2 = 64,000,000
  //   ghist   @ 64,131,072  4,096 (NB u32)
  //   gbase   @ 64,135,168  4,096 (NB+1 u32)
  //   gcursor @ 64,139,264  4,096
  //   payload @ 64,143,360  2,500,000*8 = 20,000,000 -> end 84,143,360
  const size_t FAST_NEED = 84935936;   // R5-proven size bound

  unsigned short* bfrag = (unsigned short*)ws;
  prep_weights<<<2, 256, 0, stream>>>(w_u, w_v, bfrag);

  if (ws_size >= FAST_NEED) {
    unsigned short* tmp5    = (unsigned short*)(ws + 131072);
    unsigned*       ghist   = (unsigned*)(ws + 64131072);
    unsigned*       gbase   = (unsigned*)(ws + 64135168);
    unsigned*       gcursor = (unsigned*)(ws + 64139264);
    unsigned long long* payload = (unsigned long long*)(ws + 64143360);

    const int edge_grid = (TOT_E + 8191) / 8192;  // 306
    const int gemm_grid = (N_U / 16 + 3) / 4;     // 1563

    for (int side = 0; side < 2; ++side) {
      // side 0: out_u <- tmp of x_v @ Wcum_v, dst=edge_u, src=edge_v
      // side 1: out_v <- tmp of x_u @ Wcum_u, dst=edge_v, src=edge_u
      const float* X = side ? x_u : x_v;
      const unsigned short* frag0 = bfrag + (side ? 0 : RR * 4096);
      const int* dst = side ? edge_v : edge_u;
      const int* src = side ? edge_u : edge_v;
      const float* bias = side ? bias_v : bias_u;
      float* out_side = out + (size_t)side * N_U * OO;

      gemm5_kernel<<<gemm_grid, 256, 0, stream>>>(X, frag0, tmp5);
      hipMemsetAsync(ghist, 0, NB * 4, stream);
      bucket_hist<<<edge_grid, 256, 0, stream>>>(dst, ghist);
      bucket_scan<<<1, 256, 0, stream>>>(ghist, gbase, gcursor);
      bucket_scatter<<<edge_grid, 256, 0, stream>>>(dst, src, edge_val, gcursor, payload);
      bucket_agg<<<NB, 1024, 0, stream>>>(payload, gbase, tmp5, bias, out_side);
    }
    return;
  }

  // ---------------- Fallback: proven R4 path ----------------
  unsigned short* tmp = (unsigned short*)(ws + 131072);
  float*          z   = (float*)(ws + 131072 + 12800000);
  const size_t fixed = 131072 + 12800000;
  size_t zbytes = ws_size > fixed ? ws_size - fixed : 0;
  long chunk = (long)(zbytes / (OO * 4));
  chunk -= chunk % 16;
  if (chunk < 16) chunk = 16;
  if (chunk > N_U) chunk = N_U;

  const int gemm_grid = (N_U / 16 + 3) / 4;
  const int scat_grid = EE / 4;

  for (int side = 0; side < 2; ++side) {
    const float* X = side ? x_u : x_v;
    const unsigned short* frag0 = bfrag + (side ? 0 : RR * 4096);
    const int* dst = side ? edge_v : edge_u;
    const int* src = side ? edge_u : edge_v;
    const float* bias = side ? bias_v : bias_u;
    float* out_side = out + (size_t)side * N_U * OO;

    for (long base = 0; base < N_U; base += chunk) {
      long cnt = N_U - base < chunk ? N_U - base : chunk;
      hipMemsetAsync(z, 0, (size_t)cnt * OO * 4, stream);
      for (int r = 0; r < RR; ++r) {
        gemm_kernel<<<gemm_grid, 256, 0, stream>>>(X, frag0 + r * 4096, tmp);
        scatter_kernel<<<scat_grid, 256, 0, stream>>>(
            tmp, edge_val + (size_t)r * EE, dst + (size_t)r * EE,
            src + (size_t)r * EE, z, (int)base, (int)cnt);
      }
      finalize_kernel<<<(int)(cnt / 16), 256, 0, stream>>>(
          z, bias, out_side + base * OO);
    }
  }
}

// Round 8
// 687.024 us; speedup vs baseline: 3.5267x; 3.4825x over previous
//
#include <hip/hip_runtime.h>

// Problem constants (from reference)
#define N_U 100000
#define N_V 100000
#define OO 64
#define RR 5
#define EE 500000
#define TOT_E (RR * EE)   // 2,500,000 edges per direction
#define NB 782            // buckets of 128 dst nodes (781*128=99968, last=32)

typedef short bf16x8 __attribute__((ext_vector_type(8)));
typedef float f32x4 __attribute__((ext_vector_type(4)));

__device__ __forceinline__ float bf2f(unsigned short u) {
  union { unsigned int i; float f; } x;
  x.i = ((unsigned int)u) << 16;
  return x.f;
}
__device__ __forceinline__ unsigned short f2bf(float f) {
  union { float f; unsigned int i; } x;
  x.f = f;
  unsigned int lsb = (x.i >> 16) & 1u;
  unsigned int r = x.i + 0x7fffu + lsb;   // round-to-nearest-even
  return (unsigned short)(r >> 16);
}

// ---------------------------------------------------------------------------
// Cumsum the per-relation fp32 weights, write bf16 in MFMA B-fragment order.
// bfrag layout: [side(2)=u,v][r(5)][4096]
// ---------------------------------------------------------------------------
__global__ void prep_weights(const float* __restrict__ wu,
                             const float* __restrict__ wv,
                             unsigned short* __restrict__ bfrag) {
  int side = blockIdx.x;
  const float* w = side ? wv : wu;
  for (int idx = threadIdx.x; idx < 4096; idx += 256) {
    int d = idx >> 6, o = idx & 63;
    int c = o >> 4, n = o & 15;
    int sk = d >> 5, q = (d >> 3) & 3, jj = d & 7;
    int f = c * 2 + sk;
    int lane = q * 16 + n;
    int pos = (f * 64 + lane) * 8 + jj;
    float acc = 0.f;
    for (int r = 0; r < RR; ++r) {
      acc += w[r * 4096 + idx];
      bfrag[(side * RR + r) * 4096 + pos] = f2bf(acc);
    }
  }
}

// ---------------------------------------------------------------------------
// All-5-relations GEMM: tmp5[r] = X @ Wcum[r], bf16, lane-permuted row layout
// tmp_r[row*64 + m*4 + c] = D[row][c*16+m] (8 B/lane stores).
// ---------------------------------------------------------------------------
__global__ __launch_bounds__(256) void gemm5_kernel(
    const float* __restrict__ X,
    const unsigned short* __restrict__ bfrag_side,  // [r(5)][4096]
    unsigned short* __restrict__ tmp5) {            // [r(5)][100000][64]
  __shared__ unsigned short smem[RR * 4096];
  for (int idx = threadIdx.x; idx < RR * 4096; idx += 256)
    smem[idx] = bfrag_side[idx];
  __syncthreads();

  int lane = threadIdx.x & 63;
  int wave = threadIdx.x >> 6;
  int q = lane >> 4, m = lane & 15;
  int t = blockIdx.x * 4 + wave;
  if (t >= N_U / 16) return;
  int r0 = t * 16;

  const float* xr = X + (size_t)(r0 + m) * 64;
  float4 p0 = *(const float4*)(xr + q * 8);
  float4 p1 = *(const float4*)(xr + q * 8 + 4);
  float4 p2 = *(const float4*)(xr + 32 + q * 8);
  float4 p3 = *(const float4*)(xr + 32 + q * 8 + 4);
  bf16x8 a0, a1;
  a0[0] = (short)f2bf(p0.x); a0[1] = (short)f2bf(p0.y);
  a0[2] = (short)f2bf(p0.z); a0[3] = (short)f2bf(p0.w);
  a0[4] = (short)f2bf(p1.x); a0[5] = (short)f2bf(p1.y);
  a0[6] = (short)f2bf(p1.z); a0[7] = (short)f2bf(p1.w);
  a1[0] = (short)f2bf(p2.x); a1[1] = (short)f2bf(p2.y);
  a1[2] = (short)f2bf(p2.z); a1[3] = (short)f2bf(p2.w);
  a1[4] = (short)f2bf(p3.x); a1[5] = (short)f2bf(p3.y);
  a1[6] = (short)f2bf(p3.z); a1[7] = (short)f2bf(p3.w);

  for (int r = 0; r < RR; ++r) {
    f32x4 acc[4];
#pragma unroll
    for (int c = 0; c < 4; ++c) {
      bf16x8 b0 = *(const bf16x8*)(smem + r * 4096 + ((c * 2 + 0) * 64 + lane) * 8);
      bf16x8 b1 = *(const bf16x8*)(smem + r * 4096 + ((c * 2 + 1) * 64 + lane) * 8);
      f32x4 a = {0.f, 0.f, 0.f, 0.f};
      a = __builtin_amdgcn_mfma_f32_16x16x32_bf16(a0, b0, a, 0, 0, 0);
      a = __builtin_amdgcn_mfma_f32_16x16x32_bf16(a1, b1, a, 0, 0, 0);
      acc[c] = a;
    }
    unsigned short* trow = tmp5 + (size_t)r * N_U * 64;
#pragma unroll
    for (int i = 0; i < 4; ++i) {
      ushort4 o;
      o.x = f2bf(acc[0][i]); o.y = f2bf(acc[1][i]);
      o.z = f2bf(acc[2][i]); o.w = f2bf(acc[3][i]);
      *(ushort4*)(trow + (size_t)(r0 + q * 4 + i) * 64 + m * 4) = o;
    }
  }
}

// ---------------------------------------------------------------------------
// Bucket histogram: LDS-binned, ~782 global atomics per block.
// ---------------------------------------------------------------------------
__global__ __launch_bounds__(256) void bucket_hist(
    const int* __restrict__ dst, unsigned* __restrict__ ghist) {
  __shared__ unsigned cnt[NB];
  for (int i = threadIdx.x; i < NB; i += 256) cnt[i] = 0u;
  __syncthreads();
  int base = blockIdx.x * 8192;
#pragma unroll 4
  for (int g = 0; g < 32; ++g) {
    int e = base + g * 256 + threadIdx.x;
    if (e < TOT_E) atomicAdd(&cnt[dst[e] >> 7], 1u);
  }
  __syncthreads();
  for (int b = threadIdx.x; b < NB; b += 256)
    if (cnt[b]) atomicAdd(&ghist[b], cnt[b]);
}

// ---------------------------------------------------------------------------
// Single-block exclusive scan of ghist[NB] -> gbase[NB+1] and gcursor[NB].
// Also seeds nodeoffs[N_U] = TOT_E for the aggregate's end-fetch.
// ---------------------------------------------------------------------------
__global__ __launch_bounds__(256) void bucket_scan(
    const unsigned* __restrict__ ghist, unsigned* __restrict__ gbase,
    unsigned* __restrict__ gcursor, unsigned* __restrict__ nodeoffs) {
  __shared__ unsigned wsum[4];
  int tid = threadIdx.x, lane = tid & 63, wave = tid >> 6;
  unsigned c[4]; unsigned s = 0;
#pragma unroll
  for (int k = 0; k < 4; ++k) {
    int i = tid * 4 + k;
    c[k] = (i < NB) ? ghist[i] : 0u;
    s += c[k];
  }
  unsigned incl = s;
#pragma unroll
  for (int d = 1; d < 64; d <<= 1) {
    unsigned t = __shfl_up(incl, d);
    if (lane >= d) incl += t;
  }
  if (lane == 63) wsum[wave] = incl;
  __syncthreads();
  unsigned woff = 0;
  for (int w = 0; w < 4; ++w) if (w < wave) woff += wsum[w];
  unsigned base = woff + (incl - s);
#pragma unroll
  for (int k = 0; k < 4; ++k) {
    int i = tid * 4 + k;
    if (i < NB) { gbase[i] = base; gcursor[i] = base; }
    base += c[k];
  }
  if (tid == 255) { gbase[NB] = base; nodeoffs[N_U] = TOT_E; }
}

// ---------------------------------------------------------------------------
// Multi-split scatter: per block, LDS-count its 8192 edges per bucket, reserve
// one contiguous range per (block,bucket), write ~10-entry coherent runs.
// keyU = dstLow(7b)<<19 | (r*N_U + src)(19b); valU = bf16(edge_val).
// ---------------------------------------------------------------------------
__global__ __launch_bounds__(256) void bucket_scatter(
    const int* __restrict__ dst, const int* __restrict__ src,
    const float* __restrict__ val, unsigned* __restrict__ gcursor,
    unsigned* __restrict__ keyU, unsigned short* __restrict__ valU) {
  __shared__ unsigned cnt[NB];
  for (int i = threadIdx.x; i < NB; i += 256) cnt[i] = 0u;
  __syncthreads();
  int base = blockIdx.x * 8192;
#pragma unroll 4
  for (int g = 0; g < 32; ++g) {
    int e = base + g * 256 + threadIdx.x;
    if (e < TOT_E) atomicAdd(&cnt[dst[e] >> 7], 1u);
  }
  __syncthreads();
  for (int b = threadIdx.x; b < NB; b += 256) {
    unsigned c = cnt[b];
    cnt[b] = c ? atomicAdd(&gcursor[b], c) : 0u;
  }
  __syncthreads();
#pragma unroll 2
  for (int g = 0; g < 32; ++g) {
    int e = base + g * 256 + threadIdx.x;
    if (e < TOT_E) {
      int d = dst[e];
      int r = e / EE;
      unsigned key = ((unsigned)(d & 127) << 19) | (unsigned)(r * N_U + src[e]);
      unsigned pos = atomicAdd(&cnt[d >> 7], 1u);
      keyU[pos] = key;
      valU[pos] = f2bf(val[e]);
    }
  }
}

// ---------------------------------------------------------------------------
// Per-bucket counting sort by node: 128-bin LDS histogram -> scan -> re-emit
// entries node-ordered into keyS/valS (all traffic inside the bucket's
// contiguous ~26 KB window -> L2-coherent). Writes node-level CSR offsets.
// ---------------------------------------------------------------------------
__global__ __launch_bounds__(256) void bucket_sort(
    const unsigned* __restrict__ keyU, const unsigned short* __restrict__ valU,
    const unsigned* __restrict__ gbase, unsigned* __restrict__ nodeoffs,
    unsigned* __restrict__ keyS, unsigned short* __restrict__ valS) {
  __shared__ unsigned hist[128];
  __shared__ unsigned excl[128];
  int b = blockIdx.x;
  int s = (int)gbase[b], e = (int)gbase[b + 1];
  for (int i = threadIdx.x; i < 128; i += 256) hist[i] = 0u;
  __syncthreads();
  for (int k = s + threadIdx.x; k < e; k += 256)
    atomicAdd(&hist[keyU[k] >> 19], 1u);
  __syncthreads();
  if (threadIdx.x == 0) {
    unsigned acc = (unsigned)s;
    for (int i = 0; i < 128; ++i) { unsigned h = hist[i]; excl[i] = acc; acc += h; }
  }
  __syncthreads();
  int nb0 = b * 128;
  int nodes = N_U - nb0 < 128 ? N_U - nb0 : 128;
  for (int i = threadIdx.x; i < nodes; i += 256) nodeoffs[nb0 + i] = excl[i];
  // reuse hist as fill cursor
  for (int i = threadIdx.x; i < 128; i += 256) hist[i] = excl[i];
  __syncthreads();
  for (int k = s + threadIdx.x; k < e; k += 256) {
    unsigned key = keyU[k];
    unsigned short v = valU[k];
    unsigned pos = atomicAdd(&hist[key >> 19], 1u);
    keyS[pos] = key & 0x7FFFFu;
    valS[pos] = v;
  }
}

// ---------------------------------------------------------------------------
// Node aggregate (R5-proven shape): one wave per node, register accumulate,
// one 128 B coalesced gather per entry, unroll 4, fused relu+bias writeout.
// ---------------------------------------------------------------------------
__global__ __launch_bounds__(256) void node_agg(
    const unsigned* __restrict__ keyS, const unsigned short* __restrict__ valS,
    const unsigned* __restrict__ nodeoffs,
    const unsigned short* __restrict__ tmp5,
    const float* __restrict__ bias, float* __restrict__ out) {
  int lane = threadIdx.x & 63;
  int wave = threadIdx.x >> 6;
  int node = blockIdx.x * 4 + wave;           // 25000*4 == 100000 exactly
  int s = (int)nodeoffs[node], e = (int)nodeoffs[node + 1];
  int ppos = (lane & 15) * 4 + (lane >> 4);   // position of output col `lane`
  float acc = 0.f;
  int k = s;
  for (; k + 3 < e; k += 4) {
    unsigned k0 = keyS[k + 0], k1 = keyS[k + 1];
    unsigned k2 = keyS[k + 2], k3 = keyS[k + 3];
    float v0 = bf2f(valS[k + 0]), v1 = bf2f(valS[k + 1]);
    float v2 = bf2f(valS[k + 2]), v3 = bf2f(valS[k + 3]);
    float t0 = bf2f(tmp5[(size_t)k0 * 64 + ppos]);
    float t1 = bf2f(tmp5[(size_t)k1 * 64 + ppos]);
    float t2 = bf2f(tmp5[(size_t)k2 * 64 + ppos]);
    float t3 = bf2f(tmp5[(size_t)k3 * 64 + ppos]);
    acc += v0 * t0; acc += v1 * t1; acc += v2 * t2; acc += v3 * t3;
  }
  for (; k < e; ++k)
    acc += bf2f(valS[k]) * bf2f(tmp5[(size_t)keyS[k] * 64 + ppos]);
  out[(size_t)node * 64 + lane] = fmaxf(acc + bias[lane], 0.f);
}

// ===========================================================================
// FALLBACK PATH (proven R4 atomic-scatter version, used if ws is small)
// ===========================================================================
__global__ __launch_bounds__(256) void gemm_kernel(
    const float* __restrict__ X, const unsigned short* __restrict__ bfrag,
    unsigned short* __restrict__ tmp) {
  int lane = threadIdx.x & 63;
  int wave = threadIdx.x >> 6;
  int q = lane >> 4, m = lane & 15;
  bf16x8 bf[8];
#pragma unroll
  for (int f = 0; f < 8; ++f)
    bf[f] = *(const bf16x8*)(bfrag + (f * 64 + lane) * 8);
  int t = blockIdx.x * 4 + wave;
  if (t >= N_U / 16) return;
  int r0 = t * 16;
  const float* xr = X + (size_t)(r0 + m) * 64;
  float4 p0 = *(const float4*)(xr + q * 8);
  float4 p1 = *(const float4*)(xr + q * 8 + 4);
  float4 p2 = *(const float4*)(xr + 32 + q * 8);
  float4 p3 = *(const float4*)(xr + 32 + q * 8 + 4);
  bf16x8 a0, a1;
  a0[0] = (short)f2bf(p0.x); a0[1] = (short)f2bf(p0.y);
  a0[2] = (short)f2bf(p0.z); a0[3] = (short)f2bf(p0.w);
  a0[4] = (short)f2bf(p1.x); a0[5] = (short)f2bf(p1.y);
  a0[6] = (short)f2bf(p1.z); a0[7] = (short)f2bf(p1.w);
  a1[0] = (short)f2bf(p2.x); a1[1] = (short)f2bf(p2.y);
  a1[2] = (short)f2bf(p2.z); a1[3] = (short)f2bf(p2.w);
  a1[4] = (short)f2bf(p3.x); a1[5] = (short)f2bf(p3.y);
  a1[6] = (short)f2bf(p3.z); a1[7] = (short)f2bf(p3.w);
#pragma unroll
  for (int c = 0; c < 4; ++c) {
    f32x4 acc = {0.f, 0.f, 0.f, 0.f};
    acc = __builtin_amdgcn_mfma_f32_16x16x32_bf16(a0, bf[c * 2 + 0], acc, 0, 0, 0);
    acc = __builtin_amdgcn_mfma_f32_16x16x32_bf16(a1, bf[c * 2 + 1], acc, 0, 0, 0);
#pragma unroll
    for (int i = 0; i < 4; ++i)
      tmp[(size_t)(r0 + q * 4 + i) * 64 + c * 16 + m] = f2bf(acc[i]);
  }
}

__global__ __launch_bounds__(256) void scatter_kernel(
    const unsigned short* __restrict__ tmp, const float* __restrict__ edge_val,
    const int* __restrict__ dst_idx, const int* __restrict__ src_idx,
    float* __restrict__ z, int base, int cnt) {
  int e = blockIdx.x * 4 + (threadIdx.x >> 6);
  int j = threadIdx.x & 63;
  int d = dst_idx[e] - base;
  if ((unsigned)d >= (unsigned)cnt) return;
  int s = src_idx[e];
  float w = edge_val[e];
  atomicAdd(&z[(size_t)d * 64 + j], w * bf2f(tmp[(size_t)s * 64 + j]));
}

__global__ __launch_bounds__(256) void finalize_kernel(
    const float* __restrict__ z, const float* __restrict__ bias,
    float* __restrict__ out) {
  size_t i4 = ((size_t)blockIdx.x * 256 + threadIdx.x) * 4;
  float4 zz = *(const float4*)(z + i4);
  const float4 bb = *(const float4*)(bias + (i4 & 63));
  float4 o;
  o.x = fmaxf(zz.x + bb.x, 0.f);
  o.y = fmaxf(zz.y + bb.y, 0.f);
  o.z = fmaxf(zz.z + bb.z, 0.f);
  o.w = fmaxf(zz.w + bb.w, 0.f);
  *(float4*)(out + i4) = o;
}

extern "C" void kernel_launch(void* const* d_in, const int* in_sizes, int n_in,
                              void* d_out, int out_size, void* d_ws, size_t ws_size,
                              hipStream_t stream) {
  const float* x_u      = (const float*)d_in[0];
  const float* x_v      = (const float*)d_in[1];
  const float* w_u      = (const float*)d_in[2];
  const float* w_v      = (const float*)d_in[3];
  const float* bias_u   = (const float*)d_in[4];
  const float* bias_v   = (const float*)d_in[5];
  const float* edge_val = (const float*)d_in[6];
  const int*   edge_u   = (const int*)d_in[7];
  const int*   edge_v   = (const int*)d_in[8];
  float* out = (float*)d_out;
  char* ws = (char*)d_ws;

  // Fast-path ws layout (94.5 MB; R0/R1 wrote 102.4 MB without faulting):
  //   bfrag    @ 0           131,072
  //   tmp5     @ 131,072     64,000,000            -> 64,131,072
  //   ghist    @ 64,131,072  4,096
  //   gbase    @ 64,135,168  4,096
  //   gcursor  @ 64,139,264  4,096                 -> 64,143,360
  //   nodeoffs @ 64,143,360  401,408 ((N_U+1)*4)   -> 64,544,768
  //   keyU     @ 64,544,768  10,000,000            -> 74,544,768
  //   valU     @ 74,544,768  5,000,000             -> 79,544,768
  //   keyS     @ 79,544,768  10,000,000            -> 89,544,768
  //   valS     @ 89,544,768  5,000,000             -> 94,544,768
  const size_t FAST_NEED = 94544768;

  unsigned short* bfrag = (unsigned short*)ws;
  prep_weights<<<2, 256, 0, stream>>>(w_u, w_v, bfrag);

  if (ws_size >= FAST_NEED) {
    unsigned short* tmp5     = (unsigned short*)(ws + 131072);
    unsigned*       ghist    = (unsigned*)(ws + 64131072);
    unsigned*       gbase    = (unsigned*)(ws + 64135168);
    unsigned*       gcursor  = (unsigned*)(ws + 64139264);
    unsigned*       nodeoffs = (unsigned*)(ws + 64143360);
    unsigned*       keyU     = (unsigned*)(ws + 64544768);
    unsigned short* valU     = (unsigned short*)(ws + 74544768);
    unsigned*       keyS     = (unsigned*)(ws + 79544768);
    unsigned short* valS     = (unsigned short*)(ws + 89544768);

    const int edge_grid = (TOT_E + 8191) / 8192;  // 306
    const int gemm_grid = (N_U / 16 + 3) / 4;     // 1563
    const int agg_grid  = N_U / 4;                // 25000

    for (int side = 0; side < 2; ++side) {
      // side 0: out_u <- tmp of x_v @ Wcum_v, dst=edge_u, src=edge_v
      // side 1: out_v <- tmp of x_u @ Wcum_u, dst=edge_v, src=edge_u
      const float* X = side ? x_u : x_v;
      const unsigned short* frag0 = bfrag + (side ? 0 : RR * 4096);
      const int* dst = side ? edge_v : edge_u;
      const int* src = side ? edge_u : edge_v;
      const float* bias = side ? bias_v : bias_u;
      float* out_side = out + (size_t)side * N_U * OO;

      gemm5_kernel<<<gemm_grid, 256, 0, stream>>>(X, frag0, tmp5);
      hipMemsetAsync(ghist, 0, NB * 4, stream);
      bucket_hist<<<edge_grid, 256, 0, stream>>>(dst, ghist);
      bucket_scan<<<1, 256, 0, stream>>>(ghist, gbase, gcursor, nodeoffs);
      bucket_scatter<<<edge_grid, 256, 0, stream>>>(dst, src, edge_val, gcursor,
                                                    keyU, valU);
      bucket_sort<<<NB, 256, 0, stream>>>(keyU, valU, gbase, nodeoffs, keyS, valS);
      node_agg<<<agg_grid, 256, 0, stream>>>(keyS, valS, nodeoffs, tmp5, bias,
                                             out_side);
    }
    return;
  }

  // ---------------- Fallback: proven R4 path ----------------
  unsigned short* tmp = (unsigned short*)(ws + 131072);
  float*          z   = (float*)(ws + 131072 + 12800000);
  const size_t fixed = 131072 + 12800000;
  size_t zbytes = ws_size > fixed ? ws_size - fixed : 0;
  long chunk = (long)(zbytes / (OO * 4));
  chunk -= chunk % 16;
  if (chunk < 16) chunk = 16;
  if (chunk > N_U) chunk = N_U;

  const int gemm_grid = (N_U / 16 + 3) / 4;
  const int scat_grid = EE / 4;

  for (int side = 0; side < 2; ++side) {
    const float* X = side ? x_u : x_v;
    const unsigned short* frag0 = bfrag + (side ? 0 : RR * 4096);
    const int* dst = side ? edge_v : edge_u;
    const int* src = side ? edge_u : edge_v;
    const float* bias = side ? bias_v : bias_u;
    float* out_side = out + (size_t)side * N_U * OO;

    for (long base = 0; base < N_U; base += chunk) {
      long cnt = N_U - base < chunk ? N_U - base : chunk;
      hipMemsetAsync(z, 0, (size_t)cnt * OO * 4, stream);
      for (int r = 0; r < RR; ++r) {
        gemm_kernel<<<gemm_grid, 256, 0, stream>>>(X, frag0 + r * 4096, tmp);
        scatter_kernel<<<scat_grid, 256, 0, stream>>>(
            tmp, edge_val + (size_t)r * EE, dst + (size_t)r * EE,
            src + (size_t)r * EE, z, (int)base, (int)cnt);
      }
      finalize_kernel<<<(int)(cnt / 16), 256, 0, stream>>>(
          z, bias, out_side + base * OO);
    }
  }
}

// Round 9
// 646.092 us; speedup vs baseline: 3.7501x; 1.0634x over previous
//
#include <hip/hip_runtime.h>

// Problem constants (from reference)
#define N_U 100000
#define N_V 100000
#define OO 64
#define RR 5
#define EE 500000
#define TOT_E (RR * EE)   // 2,500,000 edges per direction
#define NB 782            // buckets of 128 dst nodes (781*128=99968, last=32)
#define CAP 4096          // payload window stride per bucket (entries)
#define CAPU 3584         // max unsorted entries per bucket (mean 3197, +6.8 sigma)

typedef short bf16x8 __attribute__((ext_vector_type(8)));
typedef float f32x4 __attribute__((ext_vector_type(4)));

__device__ __forceinline__ float bf2f(unsigned short u) {
  union { unsigned int i; float f; } x;
  x.i = ((unsigned int)u) << 16;
  return x.f;
}
__device__ __forceinline__ unsigned short f2bf(float f) {
  union { float f; unsigned int i; } x;
  x.f = f;
  unsigned int lsb = (x.i >> 16) & 1u;
  unsigned int r = x.i + 0x7fffu + lsb;   // round-to-nearest-even
  return (unsigned short)(r >> 16);
}

// ---------------------------------------------------------------------------
// Cumsum the per-relation fp32 weights, write bf16 in MFMA B-fragment order.
// bfrag layout: [side(2)=u,v][r(5)][4096]
// ---------------------------------------------------------------------------
__global__ void prep_weights(const float* __restrict__ wu,
                             const float* __restrict__ wv,
                             unsigned short* __restrict__ bfrag) {
  int side = blockIdx.x;
  const float* w = side ? wv : wu;
  for (int idx = threadIdx.x; idx < 4096; idx += 256) {
    int d = idx >> 6, o = idx & 63;
    int c = o >> 4, n = o & 15;
    int sk = d >> 5, q = (d >> 3) & 3, jj = d & 7;
    int f = c * 2 + sk;
    int lane = q * 16 + n;
    int pos = (f * 64 + lane) * 8 + jj;
    float acc = 0.f;
    for (int r = 0; r < RR; ++r) {
      acc += w[r * 4096 + idx];
      bfrag[(side * RR + r) * 4096 + pos] = f2bf(acc);
    }
  }
}

// ---------------------------------------------------------------------------
// All-5-relations GEMM: tmp5[r] = X @ Wcum[r], bf16, lane-permuted row layout
// tmp_r[row*64 + m*4 + c] = D[row][c*16+m] (8 B/lane stores).
// ---------------------------------------------------------------------------
__global__ __launch_bounds__(256) void gemm5_kernel(
    const float* __restrict__ X,
    const unsigned short* __restrict__ bfrag_side,  // [r(5)][4096]
    unsigned short* __restrict__ tmp5) {            // [r(5)][100000][64]
  __shared__ unsigned short smem[RR * 4096];
  for (int idx = threadIdx.x; idx < RR * 4096; idx += 256)
    smem[idx] = bfrag_side[idx];
  __syncthreads();

  int lane = threadIdx.x & 63;
  int wave = threadIdx.x >> 6;
  int q = lane >> 4, m = lane & 15;
  int t = blockIdx.x * 4 + wave;
  if (t >= N_U / 16) return;
  int r0 = t * 16;

  const float* xr = X + (size_t)(r0 + m) * 64;
  float4 p0 = *(const float4*)(xr + q * 8);
  float4 p1 = *(const float4*)(xr + q * 8 + 4);
  float4 p2 = *(const float4*)(xr + 32 + q * 8);
  float4 p3 = *(const float4*)(xr + 32 + q * 8 + 4);
  bf16x8 a0, a1;
  a0[0] = (short)f2bf(p0.x); a0[1] = (short)f2bf(p0.y);
  a0[2] = (short)f2bf(p0.z); a0[3] = (short)f2bf(p0.w);
  a0[4] = (short)f2bf(p1.x); a0[5] = (short)f2bf(p1.y);
  a0[6] = (short)f2bf(p1.z); a0[7] = (short)f2bf(p1.w);
  a1[0] = (short)f2bf(p2.x); a1[1] = (short)f2bf(p2.y);
  a1[2] = (short)f2bf(p2.z); a1[3] = (short)f2bf(p2.w);
  a1[4] = (short)f2bf(p3.x); a1[5] = (short)f2bf(p3.y);
  a1[6] = (short)f2bf(p3.z); a1[7] = (short)f2bf(p3.w);

  for (int r = 0; r < RR; ++r) {
    f32x4 acc[4];
#pragma unroll
    for (int c = 0; c < 4; ++c) {
      bf16x8 b0 = *(const bf16x8*)(smem + r * 4096 + ((c * 2 + 0) * 64 + lane) * 8);
      bf16x8 b1 = *(const bf16x8*)(smem + r * 4096 + ((c * 2 + 1) * 64 + lane) * 8);
      f32x4 a = {0.f, 0.f, 0.f, 0.f};
      a = __builtin_amdgcn_mfma_f32_16x16x32_bf16(a0, b0, a, 0, 0, 0);
      a = __builtin_amdgcn_mfma_f32_16x16x32_bf16(a1, b1, a, 0, 0, 0);
      acc[c] = a;
    }
    unsigned short* trow = tmp5 + (size_t)r * N_U * 64;
#pragma unroll
    for (int i = 0; i < 4; ++i) {
      ushort4 o;
      o.x = f2bf(acc[0][i]); o.y = f2bf(acc[1][i]);
      o.z = f2bf(acc[2][i]); o.w = f2bf(acc[3][i]);
      *(ushort4*)(trow + (size_t)(r0 + q * 4 + i) * 64 + m * 4) = o;
    }
  }
}

// ---------------------------------------------------------------------------
// gcursor[b] = b*CAP (window base). Re-run per side (ws is re-poisoned).
// ---------------------------------------------------------------------------
__global__ void init_cursor(unsigned* __restrict__ g) {
  int i = blockIdx.x * 256 + threadIdx.x;
  if (i < NB) g[i] = (unsigned)i * CAP;
}

// ---------------------------------------------------------------------------
// Multi-split scatter into fixed stride-CAP bucket windows: per block,
// LDS-count its 8192 edges per bucket, reserve one contiguous run per
// (block,bucket) with a single global atomic, write coherent runs.
// key = dstLow(7b)<<19 | (r*N_U + src)(19b); val = bf16(edge_val).
// ---------------------------------------------------------------------------
__global__ __launch_bounds__(256) void bucket_scatter(
    const int* __restrict__ dst, const int* __restrict__ src,
    const float* __restrict__ val, unsigned* __restrict__ gcursor,
    unsigned* __restrict__ keyP, unsigned short* __restrict__ valP) {
  __shared__ unsigned cnt[NB];
  for (int i = threadIdx.x; i < NB; i += 256) cnt[i] = 0u;
  __syncthreads();
  int base = blockIdx.x * 8192;
#pragma unroll 4
  for (int g = 0; g < 32; ++g) {
    int e = base + g * 256 + threadIdx.x;
    if (e < TOT_E) atomicAdd(&cnt[dst[e] >> 7], 1u);
  }
  __syncthreads();
  for (int b = threadIdx.x; b < NB; b += 256) {
    unsigned c = cnt[b];
    cnt[b] = c ? atomicAdd(&gcursor[b], c) : 0u;
  }
  __syncthreads();
#pragma unroll 2
  for (int g = 0; g < 32; ++g) {
    int e = base + g * 256 + threadIdx.x;
    if (e < TOT_E) {
      int d = dst[e];
      int r = e / EE;
      unsigned key = ((unsigned)(d & 127) << 19) | (unsigned)(r * N_U + src[e]);
      unsigned pos = atomicAdd(&cnt[d >> 7], 1u);
      keyP[pos] = key;
      valP[pos] = f2bf(val[e]);
    }
  }
}

// ---------------------------------------------------------------------------
// In-place per-bucket counting sort by node, with node ranges padded to
// multiples of 4 (pad entries: key=0,val=0 -> contribute nothing).
// Stages the whole bucket in LDS, then rewrites the same stride-CAP window
// sorted. Emits absolute per-node offsets: nodeoffsP[b*129 + l], end at
// index `nodes` (l==128 for full buckets).
// ---------------------------------------------------------------------------
__global__ __launch_bounds__(256) void bucket_sort(
    unsigned* __restrict__ keyP, unsigned short* __restrict__ valP,
    const unsigned* __restrict__ gcursor, unsigned* __restrict__ nodeoffsP) {
  __shared__ unsigned skey[CAPU];
  __shared__ unsigned short sval[CAPU];
  __shared__ unsigned hist[128];
  __shared__ unsigned starts[129];
  __shared__ unsigned cur[128];
  int b = blockIdx.x;
  unsigned base = (unsigned)b * CAP;
  int cnt = (int)(gcursor[b] - base);
  if (cnt > CAPU) cnt = CAPU;   // ~7-sigma, statistically impossible
  for (int i = threadIdx.x; i < 128; i += 256) hist[i] = 0u;
  __syncthreads();
  for (int i = threadIdx.x; i < cnt; i += 256) {
    unsigned k = keyP[base + i];
    skey[i] = k;
    sval[i] = valP[base + i];
    atomicAdd(&hist[k >> 19], 1u);
  }
  __syncthreads();
  if (threadIdx.x == 0) {
    unsigned acc = 0u;
    for (int l = 0; l < 128; ++l) {
      starts[l] = acc;
      acc += (hist[l] + 3u) & ~3u;   // pad each node to multiple of 4
    }
    starts[128] = acc;
  }
  __syncthreads();
  int nb0 = b * 128;
  int nodes = (N_U - nb0 < 128) ? (N_U - nb0) : 128;
  for (int l = threadIdx.x; l <= nodes; l += 256)   // l==nodes writes the end
    nodeoffsP[b * 129 + l] = base + starts[l];
  for (int l = threadIdx.x; l < 128; l += 256) cur[l] = starts[l];
  __syncthreads();
  // pad slots (val=0 -> no contribution; key=0 -> valid row 0)
  for (int l = threadIdx.x; l < 128; l += 256) {
    unsigned p0 = starts[l] + hist[l], p1 = starts[l + 1];
    for (unsigned p = p0; p < p1; ++p) { keyP[base + p] = 0u; valP[base + p] = 0; }
  }
  // scatter sorted (in-place safe: everything staged in LDS above)
  for (int i = threadIdx.x; i < cnt; i += 256) {
    unsigned k = skey[i];
    unsigned pos = atomicAdd(&cur[k >> 19], 1u);
    keyP[base + pos] = k & 0x7FFFFu;
    valP[base + pos] = sval[i];
  }
}

// ---------------------------------------------------------------------------
// Node aggregate: one wave per node, register accumulate. Node ranges are
// 4-aligned and length%4==0 -> batched uint4 key + ushort4 val loads
// (6 vmem per 4 entries instead of 12), no tail code.
// ---------------------------------------------------------------------------
__global__ __launch_bounds__(256) void node_agg(
    const unsigned* __restrict__ keyP, const unsigned short* __restrict__ valP,
    const unsigned* __restrict__ nodeoffsP,
    const unsigned short* __restrict__ tmp5,
    const float* __restrict__ bias, float* __restrict__ out) {
  int lane = threadIdx.x & 63;
  int wave = threadIdx.x >> 6;
  int node = blockIdx.x * 4 + wave;           // 25000*4 == 100000 exactly
  int b = node >> 7, l = node & 127;
  unsigned s = nodeoffsP[b * 129 + l];
  unsigned e = nodeoffsP[b * 129 + l + 1];
  int ppos = (lane & 15) * 4 + (lane >> 4);   // position of output col `lane`
  float acc = 0.f;
  for (unsigned k = s; k < e; k += 4) {
    uint4 kk = *(const uint4*)(keyP + k);          // 16-B aligned (k%4==0)
    ushort4 vv = *(const ushort4*)(valP + k);      // 8-B aligned
    float t0 = bf2f(tmp5[(size_t)kk.x * 64 + ppos]);
    float t1 = bf2f(tmp5[(size_t)kk.y * 64 + ppos]);
    float t2 = bf2f(tmp5[(size_t)kk.z * 64 + ppos]);
    float t3 = bf2f(tmp5[(size_t)kk.w * 64 + ppos]);
    acc += bf2f(vv.x) * t0;
    acc += bf2f(vv.y) * t1;
    acc += bf2f(vv.z) * t2;
    acc += bf2f(vv.w) * t3;
  }
  out[(size_t)node * 64 + lane] = fmaxf(acc + bias[lane], 0.f);
}

// ===========================================================================
// FALLBACK PATH (proven R4 atomic-scatter version, used if ws is small)
// ===========================================================================
__global__ __launch_bounds__(256) void gemm_kernel(
    const float* __restrict__ X, const unsigned short* __restrict__ bfrag,
    unsigned short* __restrict__ tmp) {
  int lane = threadIdx.x & 63;
  int wave = threadIdx.x >> 6;
  int q = lane >> 4, m = lane & 15;
  bf16x8 bf[8];
#pragma unroll
  for (int f = 0; f < 8; ++f)
    bf[f] = *(const bf16x8*)(bfrag + (f * 64 + lane) * 8);
  int t = blockIdx.x * 4 + wave;
  if (t >= N_U / 16) return;
  int r0 = t * 16;
  const float* xr = X + (size_t)(r0 + m) * 64;
  float4 p0 = *(const float4*)(xr + q * 8);
  float4 p1 = *(const float4*)(xr + q * 8 + 4);
  float4 p2 = *(const float4*)(xr + 32 + q * 8);
  float4 p3 = *(const float4*)(xr + 32 + q * 8 + 4);
  bf16x8 a0, a1;
  a0[0] = (short)f2bf(p0.x); a0[1] = (short)f2bf(p0.y);
  a0[2] = (short)f2bf(p0.z); a0[3] = (short)f2bf(p0.w);
  a0[4] = (short)f2bf(p1.x); a0[5] = (short)f2bf(p1.y);
  a0[6] = (short)f2bf(p1.z); a0[7] = (short)f2bf(p1.w);
  a1[0] = (short)f2bf(p2.x); a1[1] = (short)f2bf(p2.y);
  a1[2] = (short)f2bf(p2.z); a1[3] = (short)f2bf(p2.w);
  a1[4] = (short)f2bf(p3.x); a1[5] = (short)f2bf(p3.y);
  a1[6] = (short)f2bf(p3.z); a1[7] = (short)f2bf(p3.w);
#pragma unroll
  for (int c = 0; c < 4; ++c) {
    f32x4 acc = {0.f, 0.f, 0.f, 0.f};
    acc = __builtin_amdgcn_mfma_f32_16x16x32_bf16(a0, bf[c * 2 + 0], acc, 0, 0, 0);
    acc = __builtin_amdgcn_mfma_f32_16x16x32_bf16(a1, bf[c * 2 + 1], acc, 0, 0, 0);
#pragma unroll
    for (int i = 0; i < 4; ++i)
      tmp[(size_t)(r0 + q * 4 + i) * 64 + c * 16 + m] = f2bf(acc[i]);
  }
}

__global__ __launch_bounds__(256) void scatter_kernel(
    const unsigned short* __restrict__ tmp, const float* __restrict__ edge_val,
    const int* __restrict__ dst_idx, const int* __restrict__ src_idx,
    float* __restrict__ z, int base, int cnt) {
  int e = blockIdx.x * 4 + (threadIdx.x >> 6);
  int j = threadIdx.x & 63;
  int d = dst_idx[e] - base;
  if ((unsigned)d >= (unsigned)cnt) return;
  int s = src_idx[e];
  float w = edge_val[e];
  atomicAdd(&z[(size_t)d * 64 + j], w * bf2f(tmp[(size_t)s * 64 + j]));
}

__global__ __launch_bounds__(256) void finalize_kernel(
    const float* __restrict__ z, const float* __restrict__ bias,
    float* __restrict__ out) {
  size_t i4 = ((size_t)blockIdx.x * 256 + threadIdx.x) * 4;
  float4 zz = *(const float4*)(z + i4);
  const float4 bb = *(const float4*)(bias + (i4 & 63));
  float4 o;
  o.x = fmaxf(zz.x + bb.x, 0.f);
  o.y = fmaxf(zz.y + bb.y, 0.f);
  o.z = fmaxf(zz.z + bb.z, 0.f);
  o.w = fmaxf(zz.w + bb.w, 0.f);
  *(float4*)(out + i4) = o;
}

extern "C" void kernel_launch(void* const* d_in, const int* in_sizes, int n_in,
                              void* d_out, int out_size, void* d_ws, size_t ws_size,
                              hipStream_t stream) {
  const float* x_u      = (const float*)d_in[0];
  const float* x_v      = (const float*)d_in[1];
  const float* w_u      = (const float*)d_in[2];
  const float* w_v      = (const float*)d_in[3];
  const float* bias_u   = (const float*)d_in[4];
  const float* bias_v   = (const float*)d_in[5];
  const float* edge_val = (const float*)d_in[6];
  const int*   edge_u   = (const int*)d_in[7];
  const int*   edge_v   = (const int*)d_in[8];
  float* out = (float*)d_out;
  char* ws = (char*)d_ws;

  // Fast-path ws layout (83.8 MB <= R5/R8-proven 84.9 MB):
  //   bfrag    @ 0           131,072
  //   tmp5     @ 131,072     64,000,000                 -> 64,131,072
  //   gcursor  @ 64,131,072  4,096                      -> 64,135,168
  //   nodeoffsP@ 64,135,168  409,600 (782*129*4=403,512)-> 64,544,768
  //   keyP     @ 64,544,768  782*4096*4 = 12,812,288    -> 77,357,056
  //   valP     @ 77,357,056  782*4096*2 =  6,406,144    -> 83,763,200
  const size_t FAST_NEED = 83763200;

  unsigned short* bfrag = (unsigned short*)ws;
  prep_weights<<<2, 256, 0, stream>>>(w_u, w_v, bfrag);

  if (ws_size >= FAST_NEED) {
    unsigned short* tmp5      = (unsigned short*)(ws + 131072);
    unsigned*       gcursor   = (unsigned*)(ws + 64131072);
    unsigned*       nodeoffsP = (unsigned*)(ws + 64135168);
    unsigned*       keyP      = (unsigned*)(ws + 64544768);
    unsigned short* valP      = (unsigned short*)(ws + 77357056);

    const int edge_grid = (TOT_E + 8191) / 8192;  // 306
    const int gemm_grid = (N_U / 16 + 3) / 4;     // 1563
    const int agg_grid  = N_U / 4;                // 25000

    for (int side = 0; side < 2; ++side) {
      // side 0: out_u <- tmp of x_v @ Wcum_v, dst=edge_u, src=edge_v
      // side 1: out_v <- tmp of x_u @ Wcum_u, dst=edge_v, src=edge_u
      const float* X = side ? x_u : x_v;
      const unsigned short* frag0 = bfrag + (side ? 0 : RR * 4096);
      const int* dst = side ? edge_v : edge_u;
      const int* src = side ? edge_u : edge_v;
      const float* bias = side ? bias_v : bias_u;
      float* out_side = out + (size_t)side * N_U * OO;

      init_cursor<<<4, 256, 0, stream>>>(gcursor);
      bucket_scatter<<<edge_grid, 256, 0, stream>>>(dst, src, edge_val, gcursor,
                                                    keyP, valP);
      bucket_sort<<<NB, 256, 0, stream>>>(keyP, valP, gcursor, nodeoffsP);
      gemm5_kernel<<<gemm_grid, 256, 0, stream>>>(X, frag0, tmp5);
      node_agg<<<agg_grid, 256, 0, stream>>>(keyP, valP, nodeoffsP, tmp5, bias,
                                             out_side);
    }
    return;
  }

  // ---------------- Fallback: proven R4 path ----------------
  unsigned short* tmp = (unsigned short*)(ws + 131072);
  float*          z   = (float*)(ws + 131072 + 12800000);
  const size_t fixed = 131072 + 12800000;
  size_t zbytes = ws_size > fixed ? ws_size - fixed : 0;
  long chunk = (long)(zbytes / (OO * 4));
  chunk -= chunk % 16;
  if (chunk < 16) chunk = 16;
  if (chunk > N_U) chunk = N_U;

  const int gemm_grid = (N_U / 16 + 3) / 4;
  const int scat_grid = EE / 4;

  for (int side = 0; side < 2; ++side) {
    const float* X = side ? x_u : x_v;
    const unsigned short* frag0 = bfrag + (side ? 0 : RR * 4096);
    const int* dst = side ? edge_v : edge_u;
    const int* src = side ? edge_u : edge_v;
    const float* bias = side ? bias_v : bias_u;
    float* out_side = out + (size_t)side * N_U * OO;

    for (long base = 0; base < N_U; base += chunk) {
      long cnt = N_U - base < chunk ? N_U - base : chunk;
      hipMemsetAsync(z, 0, (size_t)cnt * OO * 4, stream);
      for (int r = 0; r < RR; ++r) {
        gemm_kernel<<<gemm_grid, 256, 0, stream>>>(X, frag0 + r * 4096, tmp);
        scatter_kernel<<<scat_grid, 256, 0, stream>>>(
            tmp, edge_val + (size_t)r * EE, dst + (size_t)r * EE,
            src + (size_t)r * EE, z, (int)base, (int)cnt);
      }
      finalize_kernel<<<(int)(cnt / 16), 256, 0, stream>>>(
          z, bias, out_side + base * OO);
    }
  }
}